// Round 4
// baseline (104.765 us; speedup 1.0000x reference)
//
#include <hip/hip_runtime.h>
#include <hip/hip_bf16.h>
#include <cstdint>

#define NV 64
#define NH 128
#define NB 16384
#define W2_ELEMS (NH * NV * NV)   // 524288
#define W1_ELEMS (NV * NH)        // 8192

typedef __bf16 bf16x8_t __attribute__((ext_vector_type(8)));
typedef float f32x4_t __attribute__((ext_vector_type(4)));
typedef uint32_t u32x4_t __attribute__((ext_vector_type(4)));

__device__ __forceinline__ uint32_t bf16_rne(float f) {
  uint32_t u = __float_as_uint(f);
  return (u + 0x7fffu + ((u >> 16) & 1u)) >> 16;
}

// Pre-pass: convert W2 (f32, 2 MB) and W1 (f32, 32 KB) to bf16 in d_ws.
// 520 blocks x 256 threads x 4 elements = exactly W2_ELEMS + W1_ELEMS.
__global__ void cvt_kernel(const float* __restrict__ w1f,
                           const float* __restrict__ w2f,
                           uint16_t* __restrict__ wsW2,
                           uint16_t* __restrict__ wsW1) {
  int base = (blockIdx.x * 256 + threadIdx.x) * 4;
  const float* src;
  uint16_t* dst;
  int off;
  if (base < W2_ELEMS) { src = w2f; dst = wsW2; off = base; }
  else                 { src = w1f; dst = wsW1; off = base - W2_ELEMS; }
  float4 v = *(const float4*)(src + off);
  uint2 p;
  p.x = (bf16_rne(v.y) << 16) | bf16_rne(v.x);
  p.y = (bf16_rne(v.w) << 16) | bf16_rne(v.z);
  *(uint2*)(dst + off) = p;
}

// C[m,h] = sum_k G[m,k]*Bx[h,k], k<4096: G=0.5*x_i*x_j (k=i*64+j), Bx=W2[h,i,j]
//          k in [4096,4160): G=x_j, Bx=W1[j,h] -> a = bias + C; psi = prod_h cos(a)
// All-f32 I/O; W1/W2 pre-converted to bf16 in ws. btile cols XOR-swizzled
// (kg ^ ((h>>1)&3)) so ds_write/ds_read_b128 are <=2-way (free, m136).
__launch_bounds__(512, 2)
__global__ void rbm_kernel(const float* __restrict__ xg,
                           const float* __restrict__ biasg,
                           const __hip_bfloat16* __restrict__ w1g,
                           const __hip_bfloat16* __restrict__ w2g,
                           float* __restrict__ outg) {
  __shared__ __align__(16) __hip_bfloat16 btile[2][NH * 32]; // 2 x 8 KB W2 chunk
  __shared__ __align__(16) __hip_bfloat16 xtile[64 * 72];    // x rows bf16, stride 72
  __shared__ __align__(16) __hip_bfloat16 w1t[NH * 72];      // W1^T, stride 72
  __shared__ float part[4][64];

  const int tid  = threadIdx.x;
  const int wv   = tid >> 6;   // wave 0..7
  const int lane = tid & 63;
  const int c15  = lane & 15;
  const int q    = lane >> 4;  // quad
  const int wm   = wv & 1;     // m half (32 rows)
  const int hq   = wv >> 1;    // h quarter (32 cols)
  const int mblk = blockIdx.x * 64;

  // staging geometry: wave wv stages h rows [16wv,16wv+16)
  const int srow = wv * 16 + (lane >> 2);
  const int skg  = lane & 3;                 // fetched col group (of 8)
  const int dcg  = skg ^ ((srow >> 1) & 3);  // swizzled dest col group
  const size_t gbase = (size_t)srow * 4096 + skg * 8;
  const int dsoff = srow * 32 + dcg * 8;

  // prefetch W2 chunk 0 (bf16 from ws)
  uint4 pre = *(const uint4*)(w2g + gbase);

  // stage x tile: read f32, convert RNE, store bf16 (64 x 64, stride 72)
  {
    int row = tid >> 3, grp = tid & 7;
    const float* p = xg + (size_t)(mblk + row) * NV + grp * 8;
    float4 a = *(const float4*)(p);
    float4 b = *(const float4*)(p + 4);
    uint4 o;
    o.x = (bf16_rne(a.y) << 16) | bf16_rne(a.x);
    o.y = (bf16_rne(a.w) << 16) | bf16_rne(a.z);
    o.z = (bf16_rne(b.y) << 16) | bf16_rne(b.x);
    o.w = (bf16_rne(b.w) << 16) | bf16_rne(b.z);
    *(uint4*)(&xtile[row * 72 + grp * 8]) = o;
  }
  // build W1^T tile: w1t[h*72 + j] = W1bf[j*128 + h] (all 128 h)
  {
    int j = tid >> 3, hgrp = tid & 7;
#pragma unroll
    for (int half = 0; half < 2; ++half) {
      int hg = half * 8 + hgrp;
      uint4 v = *(const uint4*)(w1g + (size_t)j * NH + hg * 8);
      const uint32_t d[4] = {v.x, v.y, v.z, v.w};
#pragma unroll
      for (int e = 0; e < 4; ++e) {
        int h0 = hg * 8 + 2 * e;
        ((uint16_t*)w1t)[(h0 + 0) * 72 + j] = (uint16_t)(d[e] & 0xffffu);
        ((uint16_t*)w1t)[(h0 + 1) * 72 + j] = (uint16_t)(d[e] >> 16);
      }
    }
  }
  // per-lane x values for A-fragment generation, full f32:
  // rows m = mblk + 32*wm + 16*im + c15 ; cols j = jh*32 + q*8 + t
  float xf[2][2][8];
#pragma unroll
  for (int im = 0; im < 2; ++im) {
    int row = mblk + 32 * wm + 16 * im + c15;
#pragma unroll
    for (int jh = 0; jh < 2; ++jh) {
      const float* p = xg + (size_t)row * NV + jh * 32 + q * 8;
      float4 a = *(const float4*)(p);
      float4 b = *(const float4*)(p + 4);
      xf[im][jh][0] = a.x; xf[im][jh][1] = a.y;
      xf[im][jh][2] = a.z; xf[im][jh][3] = a.w;
      xf[im][jh][4] = b.x; xf[im][jh][5] = b.y;
      xf[im][jh][6] = b.z; xf[im][jh][7] = b.w;
    }
  }

  // B-fragment LDS offsets (swizzle-adjusted), fixed per wave
  int boff[2];
#pragma unroll
  for (int ih = 0; ih < 2; ++ih) {
    int hrow = 32 * hq + 16 * ih + c15;
    boff[ih] = hrow * 32 + (q ^ ((hrow >> 1) & 3)) * 8;
  }

  f32x4_t acc[2][2];
#pragma unroll
  for (int im = 0; im < 2; ++im)
#pragma unroll
    for (int ih = 0; ih < 2; ++ih)
      acc[im][ih] = (f32x4_t)0.0f;

  float scur[2] = {0.f, 0.f};

#pragma unroll 2
  for (int c = 0; c < 128; ++c) {
    const int buf = c & 1;
    *(uint4*)(&btile[buf][dsoff]) = pre;  // publish chunk c
    if (c + 1 < 128) pre = *(const uint4*)(w2g + gbase + (size_t)(c + 1) * 32);
    __syncthreads();

    const int jh = c & 1;
    if (jh == 0) {  // new i: s_i = 0.5 * x[m][i] (bf16 from xtile)
      int i = c >> 1;
#pragma unroll
      for (int im = 0; im < 2; ++im) {
        int row = 32 * wm + 16 * im + c15;
        uint16_t b = ((const uint16_t*)xtile)[row * 72 + i];
        scur[im] = 0.5f * __uint_as_float(((uint32_t)b) << 16);
      }
    }
    // A fragments: a[k] = s_i * x_j, truncate-pack to bf16
    bf16x8_t afrag[2];
#pragma unroll
    for (int im = 0; im < 2; ++im) {
      u32x4_t adv;
#pragma unroll
      for (int t = 0; t < 4; ++t) {
        uint32_t p0 = __float_as_uint(scur[im] * xf[im][jh][2 * t]);
        uint32_t p1 = __float_as_uint(scur[im] * xf[im][jh][2 * t + 1]);
        adv[t] = __builtin_amdgcn_perm(p1, p0, 0x07060302); // pack high halves
      }
      afrag[im] = __builtin_bit_cast(bf16x8_t, adv);
    }
#pragma unroll
    for (int ih = 0; ih < 2; ++ih) {
      bf16x8_t bfrag = *(const bf16x8_t*)(&btile[buf][boff[ih]]);
#pragma unroll
      for (int im = 0; im < 2; ++im)
        acc[im][ih] = __builtin_amdgcn_mfma_f32_16x16x32_bf16(
            afrag[im], bfrag, acc[im][ih], 0, 0, 0);
    }
  }

  // order-1 tail: A = x, B = W1^T from LDS
#pragma unroll
  for (int cc = 0; cc < 2; ++cc) {
    bf16x8_t afrag[2];
#pragma unroll
    for (int im = 0; im < 2; ++im) {
      u32x4_t adv;
#pragma unroll
      for (int t = 0; t < 4; ++t) {
        uint32_t p0 = __float_as_uint(xf[im][cc][2 * t]);
        uint32_t p1 = __float_as_uint(xf[im][cc][2 * t + 1]);
        adv[t] = __builtin_amdgcn_perm(p1, p0, 0x07060302);
      }
      afrag[im] = __builtin_bit_cast(bf16x8_t, adv);
    }
#pragma unroll
    for (int ih = 0; ih < 2; ++ih) {
      int hrow = 32 * hq + 16 * ih + c15;
      bf16x8_t bfrag = *(const bf16x8_t*)(&w1t[hrow * 72 + cc * 32 + q * 8]);
#pragma unroll
      for (int im = 0; im < 2; ++im)
        acc[im][ih] = __builtin_amdgcn_mfma_f32_16x16x32_bf16(
            afrag[im], bfrag, acc[im][ih], 0, 0, 0);
    }
  }

  // epilogue: a += bias (f32); cos; product over h
  float bs[2];
#pragma unroll
  for (int ih = 0; ih < 2; ++ih)
    bs[ih] = biasg[32 * hq + 16 * ih + c15];

  float prod[2][4];
#pragma unroll
  for (int im = 0; im < 2; ++im)
#pragma unroll
    for (int r = 0; r < 4; ++r)
      prod[im][r] = cosf(acc[im][0][r] + bs[0]) * cosf(acc[im][1][r] + bs[1]);

#pragma unroll
  for (int ofs = 1; ofs < 16; ofs <<= 1)
#pragma unroll
    for (int im = 0; im < 2; ++im)
#pragma unroll
      for (int r = 0; r < 4; ++r)
        prod[im][r] *= __shfl_xor(prod[im][r], ofs, 16);

  if (c15 == 0) {
#pragma unroll
    for (int im = 0; im < 2; ++im)
#pragma unroll
      for (int r = 0; r < 4; ++r)
        part[hq][32 * wm + 16 * im + 4 * q + r] = prod[im][r];
  }
  __syncthreads();
  if (tid < 64) {
    float f = part[0][tid] * part[1][tid] * part[2][tid] * part[3][tid];
    outg[mblk + tid] = f;
  }
}

extern "C" void kernel_launch(void* const* d_in, const int* in_sizes, int n_in,
                              void* d_out, int out_size, void* d_ws, size_t ws_size,
                              hipStream_t stream) {
  const float* x   = (const float*)d_in[0];
  const float* w1f = (const float*)d_in[1];
  const float* w2f = (const float*)d_in[2];
  const float* hb  = (const float*)d_in[3];
  float* out = (float*)d_out;
  uint16_t* wsW2 = (uint16_t*)d_ws;          // 1 MB bf16 W2 [h][i][j]
  uint16_t* wsW1 = wsW2 + W2_ELEMS;          // 16 KB bf16 W1 [j][h]
  (void)in_sizes; (void)n_in; (void)out_size; (void)ws_size;

  cvt_kernel<<<(W2_ELEMS + W1_ELEMS) / (256 * 4), 256, 0, stream>>>(
      w1f, w2f, wsW2, wsW1);
  rbm_kernel<<<NB / 64, 512, 0, stream>>>(
      x, hb, (const __hip_bfloat16*)wsW1, (const __hip_bfloat16*)wsW2, out);
}

// Round 5
// 99.645 us; speedup vs baseline: 1.0514x; 1.0514x over previous
//
#include <hip/hip_runtime.h>
#include <hip/hip_bf16.h>
#include <cstdint>

#define NV 64
#define NH 128
#define NB 16384
#define W2_ELEMS (NH * NV * NV)   // 524288
#define W1_ELEMS (NV * NH)        // 8192

typedef __bf16 bf16x8_t __attribute__((ext_vector_type(8)));
typedef float f32x4_t __attribute__((ext_vector_type(4)));
typedef float f32x2_t __attribute__((ext_vector_type(2)));
typedef uint32_t u32x4_t __attribute__((ext_vector_type(4)));
typedef uint32_t u32x2_t __attribute__((ext_vector_type(2)));

__device__ __forceinline__ uint32_t bf16_rne(float f) {
  uint32_t u = __float_as_uint(f);
  return (u + 0x7fffu + ((u >> 16) & 1u)) >> 16;
}

// Pre-pass: wsW2[h*4096 + k] = bf16(0.5 * W2[h][k])  (0.5 folded in here)
//           wsW1t[h*64 + j]  = bf16(W1[j][h])        (pre-transposed)
__global__ void cvt_kernel(const float* __restrict__ w1f,
                           const float* __restrict__ w2f,
                           uint16_t* __restrict__ wsW2,
                           uint16_t* __restrict__ wsW1t) {
  int base = (blockIdx.x * 256 + threadIdx.x) * 4;
  if (base < W2_ELEMS) {
    float4 v = *(const float4*)(w2f + base);
    uint2 p;
    p.x = (bf16_rne(0.5f * v.y) << 16) | bf16_rne(0.5f * v.x);
    p.y = (bf16_rne(0.5f * v.w) << 16) | bf16_rne(0.5f * v.z);
    *(uint2*)(wsW2 + base) = p;
  } else {
    int off = base - W2_ELEMS;
    float4 v = *(const float4*)(w1f + off);
    const float d[4] = {v.x, v.y, v.z, v.w};
#pragma unroll
    for (int e = 0; e < 4; ++e) {
      int idx = off + e;
      int j = idx >> 7, h = idx & 127;
      wsW1t[h * 64 + j] = (uint16_t)bf16_rne(d[e]);
    }
  }
}

// C[m,h] = sum_k G[m,k]*Bx[h,k]; k<4096: G=x_i*x_j (k=i*64+j), Bx=0.5*W2[h,i,j]
//          k in [4096,4160): G=x_j, Bx=W1T[h,j].  a = bias + C; psi = prod_h cos(a)
// K-loop: BK=64 (one i per chunk), double-buffered LDS, loads issued at TOP of
// compute phase, ds_write at BOTTOM -> vmcnt satisfied before the barrier drain.
// LDS swizzle: 16B-group g stored at (g ^ (h&7)) -> b128 ops at 8-phase minimum.
__launch_bounds__(512, 2)
__global__ void rbm_kernel(const float* __restrict__ xg,
                           const float* __restrict__ biasg,
                           const __hip_bfloat16* __restrict__ w1tg,
                           const __hip_bfloat16* __restrict__ w2g,
                           float* __restrict__ outg) {
  __shared__ __align__(16) __hip_bfloat16 btile[2][NH * 64]; // 2 x 16 KB
  __shared__ __align__(16) float xtile[64 * 68];             // f32 x rows, stride 68
  __shared__ float part[4][64];

  const int tid  = threadIdx.x;
  const int wv   = tid >> 6;
  const int lane = tid & 63;
  const int c15  = lane & 15;
  const int q    = lane >> 4;
  const int wm   = wv & 1;     // m half (32 rows)
  const int hq   = wv >> 1;    // h quarter (32 cols)
  const int mblk = blockIdx.x * 64;

  // staging: thread -> h row (tid>>2), 16B groups g0=tid&3 and g0+4
  const int sh = tid >> 2;
  const int g0 = tid & 3, g1 = g0 + 4;
  const __hip_bfloat16* w2row = w2g + (size_t)sh * 4096;
  const int d0 = sh * 64 + ((g0 ^ (sh & 7)) * 8);
  const int d1 = sh * 64 + ((g1 ^ (sh & 7)) * 8);

  // stage x tile as f32 (64 rows x 64 cols, stride 68: rows step 4 banks)
  {
    int row = tid >> 3, grp = tid & 7;
    const float* p = xg + (size_t)(mblk + row) * NV + grp * 8;
    float4 a = *(const float4*)(p);
    float4 b = *(const float4*)(p + 4);
    *(float4*)(&xtile[row * 68 + grp * 8]) = a;
    *(float4*)(&xtile[row * 68 + grp * 8 + 4]) = b;
  }

  // per-lane x values (f32 pairs): rows m = mblk+32wm+16im+c15, cols jh*32+q*8+2t{,+1}
  f32x2_t xf[2][2][4];
#pragma unroll
  for (int im = 0; im < 2; ++im) {
    int row = mblk + 32 * wm + 16 * im + c15;
#pragma unroll
    for (int jh = 0; jh < 2; ++jh) {
      const float* p = xg + (size_t)row * NV + jh * 32 + q * 8;
      float4 a = *(const float4*)(p);
      float4 b = *(const float4*)(p + 4);
      xf[im][jh][0] = f32x2_t{a.x, a.y};
      xf[im][jh][1] = f32x2_t{a.z, a.w};
      xf[im][jh][2] = f32x2_t{b.x, b.y};
      xf[im][jh][3] = f32x2_t{b.z, b.w};
    }
  }

  // B-fragment LDS offsets per (ih, jh), swizzle-adjusted
  int boff[2][2];
#pragma unroll
  for (int ih = 0; ih < 2; ++ih) {
    int hrow = 32 * hq + 16 * ih + c15;
#pragma unroll
    for (int jh = 0; jh < 2; ++jh)
      boff[ih][jh] = hrow * 64 + (((jh * 4 + q) ^ (hrow & 7)) * 8);
  }

  // stage chunk 0 into buf 0
  {
    uint4 p0 = *(const uint4*)(w2row + g0 * 8);
    uint4 p1 = *(const uint4*)(w2row + g1 * 8);
    *(uint4*)(&btile[0][d0]) = p0;
    *(uint4*)(&btile[0][d1]) = p1;
  }
  __syncthreads();

  f32x4_t acc[2][2];
#pragma unroll
  for (int im = 0; im < 2; ++im)
#pragma unroll
    for (int ih = 0; ih < 2; ++ih)
      acc[im][ih] = (f32x4_t)0.0f;

#pragma unroll 2
  for (int c = 0; c < 64; ++c) {
    const int buf = c & 1;
    uint4 p0, p1;
    if (c < 63) {  // issue prefetch at TOP: whole compute phase hides latency
      const __hip_bfloat16* src = w2row + (c + 1) * 64;
      p0 = *(const uint4*)(src + g0 * 8);
      p1 = *(const uint4*)(src + g1 * 8);
    }
    float s[2];  // s_i = x[m][i], i = c (0.5 already folded into W2)
#pragma unroll
    for (int im = 0; im < 2; ++im)
      s[im] = xtile[(32 * wm + 16 * im + c15) * 68 + c];

#pragma unroll
    for (int jh = 0; jh < 2; ++jh) {
      bf16x8_t afrag[2];
#pragma unroll
      for (int im = 0; im < 2; ++im) {
        const f32x2_t s2 = f32x2_t{s[im], s[im]};
        u32x4_t adv;
#pragma unroll
        for (int t = 0; t < 4; ++t) {
          f32x2_t pr = s2 * xf[im][jh][t];  // v_pk_mul_f32
          u32x2_t u = __builtin_bit_cast(u32x2_t, pr);
          adv[t] = __builtin_amdgcn_perm(u[1], u[0], 0x07060302);  // pack hi halves
        }
        afrag[im] = __builtin_bit_cast(bf16x8_t, adv);
      }
#pragma unroll
      for (int ih = 0; ih < 2; ++ih) {
        bf16x8_t bfrag = *(const bf16x8_t*)(&btile[buf][boff[ih][jh]]);
#pragma unroll
        for (int im = 0; im < 2; ++im)
          acc[im][ih] = __builtin_amdgcn_mfma_f32_16x16x32_bf16(
              afrag[im], bfrag, acc[im][ih], 0, 0, 0);
      }
    }
    if (c < 63) {  // publish chunk c+1 at BOTTOM, then barrier
      *(uint4*)(&btile[buf ^ 1][d0]) = p0;
      *(uint4*)(&btile[buf ^ 1][d1]) = p1;
      __syncthreads();
    }
  }

  // order-1 tail: A = x_j, B = W1T rows straight from L2 (pre-transposed in ws)
#pragma unroll
  for (int cc = 0; cc < 2; ++cc) {
    bf16x8_t afrag[2];
#pragma unroll
    for (int im = 0; im < 2; ++im) {
      u32x4_t adv;
#pragma unroll
      for (int t = 0; t < 4; ++t) {
        u32x2_t u = __builtin_bit_cast(u32x2_t, xf[im][cc][t]);
        adv[t] = __builtin_amdgcn_perm(u[1], u[0], 0x07060302);
      }
      afrag[im] = __builtin_bit_cast(bf16x8_t, adv);
    }
#pragma unroll
    for (int ih = 0; ih < 2; ++ih) {
      int hrow = 32 * hq + 16 * ih + c15;
      bf16x8_t bfrag = *(const bf16x8_t*)(w1tg + hrow * 64 + cc * 32 + q * 8);
#pragma unroll
      for (int im = 0; im < 2; ++im)
        acc[im][ih] = __builtin_amdgcn_mfma_f32_16x16x32_bf16(
            afrag[im], bfrag, acc[im][ih], 0, 0, 0);
    }
  }

  // epilogue: a += bias; cos; product over h (16-lane butterfly + LDS combine)
  float bs[2];
#pragma unroll
  for (int ih = 0; ih < 2; ++ih)
    bs[ih] = biasg[32 * hq + 16 * ih + c15];

  float prod[2][4];
#pragma unroll
  for (int im = 0; im < 2; ++im)
#pragma unroll
    for (int r = 0; r < 4; ++r)
      prod[im][r] = cosf(acc[im][0][r] + bs[0]) * cosf(acc[im][1][r] + bs[1]);

#pragma unroll
  for (int ofs = 1; ofs < 16; ofs <<= 1)
#pragma unroll
    for (int im = 0; im < 2; ++im)
#pragma unroll
      for (int r = 0; r < 4; ++r)
        prod[im][r] *= __shfl_xor(prod[im][r], ofs, 16);

  if (c15 == 0) {
#pragma unroll
    for (int im = 0; im < 2; ++im)
#pragma unroll
      for (int r = 0; r < 4; ++r)
        part[hq][32 * wm + 16 * im + 4 * q + r] = prod[im][r];
  }
  __syncthreads();
  if (tid < 64) {
    float f = part[0][tid] * part[1][tid] * part[2][tid] * part[3][tid];
    outg[mblk + tid] = f;
  }
}

extern "C" void kernel_launch(void* const* d_in, const int* in_sizes, int n_in,
                              void* d_out, int out_size, void* d_ws, size_t ws_size,
                              hipStream_t stream) {
  const float* x   = (const float*)d_in[0];
  const float* w1f = (const float*)d_in[1];
  const float* w2f = (const float*)d_in[2];
  const float* hb  = (const float*)d_in[3];
  float* out = (float*)d_out;
  uint16_t* wsW2  = (uint16_t*)d_ws;         // 1 MB bf16 0.5*W2 [h][i*64+j]
  uint16_t* wsW1t = wsW2 + W2_ELEMS;         // 16 KB bf16 W1^T [h][j]
  (void)in_sizes; (void)n_in; (void)out_size; (void)ws_size;

  cvt_kernel<<<(W2_ELEMS + W1_ELEMS) / (256 * 4), 256, 0, stream>>>(
      w1f, w2f, wsW2, wsW1t);
  rbm_kernel<<<NB / 64, 512, 0, stream>>>(
      x, hb, (const __hip_bfloat16*)wsW1t, (const __hip_bfloat16*)wsW2, out);
}